// Round 1
// baseline (793.486 us; speedup 1.0000x reference)
//
#include <hip/hip_runtime.h>

#define N_NODES 100000
#define N_EDGES 800000
#define D 128

// ---------------- degree count (int atomics) ----------------
__global__ void k_deg(const int* __restrict__ dst, int* __restrict__ degs) {
  int e = blockIdx.x * 256 + threadIdx.x;
  if (e < N_EDGES) atomicAdd(&degs[dst[e]], 1);
}

// ---------------- 2-level exclusive scan over degrees ----------------
__global__ void k_scan1(const int* __restrict__ degs, int* __restrict__ offs,
                        int* __restrict__ aux) {
  __shared__ int s[256];
  int tid = threadIdx.x;
  int i = blockIdx.x * 256 + tid;
  int v = (i < N_NODES) ? degs[i] : 0;
  int sum = v;
  s[tid] = sum; __syncthreads();
  for (int off = 1; off < 256; off <<= 1) {
    int t = (tid >= off) ? s[tid - off] : 0;
    __syncthreads();
    sum += t; s[tid] = sum;
    __syncthreads();
  }
  if (i < N_NODES) offs[i] = sum - v;      // exclusive within block
  if (tid == 255) aux[blockIdx.x] = sum;   // block total
}

__global__ void k_scan2(const int* __restrict__ aux, int* __restrict__ aux2, int nblk) {
  __shared__ int s[512];
  int tid = threadIdx.x;
  int v = (tid < nblk) ? aux[tid] : 0;
  int sum = v;
  s[tid] = sum; __syncthreads();
  for (int off = 1; off < 512; off <<= 1) {
    int t = (tid >= off) ? s[tid - off] : 0;
    __syncthreads();
    sum += t; s[tid] = sum;
    __syncthreads();
  }
  aux2[tid] = sum - v;                     // exclusive block offsets
}

__global__ void k_scan3(int* __restrict__ offs, const int* __restrict__ aux2,
                        const int* __restrict__ degs, float* __restrict__ dinv) {
  int i = blockIdx.x * 256 + threadIdx.x;
  if (i < N_NODES) {
    offs[i] += aux2[blockIdx.x];
    dinv[i] = rsqrtf(fmaxf((float)degs[i], 1.0f));
  }
}

// ---------------- CSR fill (counting sort by dst) ----------------
__global__ void k_fill(const int* __restrict__ src, const int* __restrict__ dst,
                       const int* __restrict__ offs, int* __restrict__ cursor,
                       int* __restrict__ csr) {
  int e = blockIdx.x * 256 + threadIdx.x;
  if (e < N_EDGES) {
    int d = dst[e];
    int pos = offs[d] + atomicAdd(&cursor[d], 1);
    csr[pos] = src[e];
  }
}

// ---------------- per-node MLP -> prob -> xk = x + alpha*x_node ----------------
// 2 nodes per 256-block iteration; thread j holds W1 row j in 128 VGPRs.
__global__ __launch_bounds__(256, 2)
void k_mlp(const float* __restrict__ x, const float* __restrict__ w1,
           const float* __restrict__ w2, const float* __restrict__ b1,
           const float* __restrict__ b2, const float* __restrict__ emb,
           const float* __restrict__ alpha_p, float* __restrict__ xk) {
  __shared__ __align__(16) float xs[256];
  __shared__ float red[4];
  __shared__ float probs[2];
  int tid = threadIdx.x;
  int j = tid & 127;
  int half = tid >> 7;

  float4 w1v[32];
  const float4* w14 = (const float4*)(w1 + j * 128);
  #pragma unroll
  for (int m = 0; m < 32; m++) w1v[m] = w14[m];

  float bj = b1[j];
  float wdiff = w2[128 + j] - w2[j];
  float db2 = b2[1] - b2[0];
  float e0 = emb[j], e1 = emb[128 + j];
  float al = alpha_p[0];

  for (int pr = blockIdx.x; pr < N_NODES / 2; pr += gridDim.x) {
    int node = pr * 2 + half;
    xs[tid] = x[node * 128 + j];
    __syncthreads();

    float acc = bj;
    const float4* xs4 = (const float4*)(xs + half * 128);
    #pragma unroll
    for (int m = 0; m < 32; m++) {
      float4 xv = xs4[m];
      acc += xv.x * w1v[m].x + xv.y * w1v[m].y + xv.z * w1v[m].z + xv.w * w1v[m].w;
    }
    float v = fmaxf(acc, 0.0f) * wdiff;
    #pragma unroll
    for (int off = 32; off; off >>= 1) v += __shfl_down(v, off);
    int wave = tid >> 6;
    if ((tid & 63) == 0) red[wave] = v;
    __syncthreads();
    if (tid == 0)   { float z = red[0] + red[1] + db2; probs[0] = 1.f / (1.f + expf(-z)); }
    if (tid == 128) { float z = red[2] + red[3] + db2; probs[1] = 1.f / (1.f + expf(-z)); }
    __syncthreads();
    float p = probs[half];
    float xn = (1.f - p) * e0 + p * e1;
    xk[node * 128 + j] = xs[tid] + al * xn;
    __syncthreads();   // xs/red/probs reused next iteration
  }
}

// ---------------- Laplacian gather passes (wave per node, no float atomics) ----
// PASS 1: feat=xk  -> xk1 = xk - dinv*sum ; hi = 0.5*xk + 0.3*xk1
// PASS 2: feat=xk1 -> xk2 = xk1 - dinv*sum; hi += 0.2*xk2
template <int PASS>
__global__ void k_gather(const float* __restrict__ feat, float* __restrict__ feat_out,
                         float* __restrict__ hi, const int* __restrict__ csr,
                         const int* __restrict__ offs, const int* __restrict__ degs,
                         const float* __restrict__ dinv) {
  int node = blockIdx.x * 4 + (threadIdx.x >> 6);
  if (node >= N_NODES) return;
  int lane = threadIdx.x & 63;
  int start = offs[node];
  int cnt = degs[node];
  const float2* f2 = (const float2*)feat;
  float2 acc = make_float2(0.f, 0.f);
  int j = 0;
  for (; j + 1 < cnt; j += 2) {
    int s0 = csr[start + j], s1 = csr[start + j + 1];
    float dv0 = dinv[s0], dv1 = dinv[s1];
    float2 v0 = f2[s0 * 64 + lane];
    float2 v1 = f2[s1 * 64 + lane];
    acc.x += v0.x * dv0 + v1.x * dv1;
    acc.y += v0.y * dv0 + v1.y * dv1;
  }
  if (j < cnt) {
    int s0 = csr[start + j];
    float dv0 = dinv[s0];
    float2 v0 = f2[s0 * 64 + lane];
    acc.x += v0.x * dv0; acc.y += v0.y * dv0;
  }
  float dvi = dinv[node];
  float2 old = f2[node * 64 + lane];
  float2 nw = make_float2(old.x - acc.x * dvi, old.y - acc.y * dvi);
  float2* hi2 = (float2*)hi;
  if (PASS == 1) {
    ((float2*)feat_out)[node * 64 + lane] = nw;
    hi2[node * 64 + lane] = make_float2(0.5f * old.x + 0.3f * nw.x,
                                        0.5f * old.y + 0.3f * nw.y);
  } else {
    float2 h = hi2[node * 64 + lane];
    hi2[node * 64 + lane] = make_float2(h.x + 0.2f * nw.x, h.y + 0.2f * nw.y);
  }
}

// ---------------- precompute merged weight matrix Wall[384][128] -------------
// k<128 : C[k][d] = lin_w[d][k]
// 128<=k<384: Wall[k][d] = sum_j weights[k-128][j] * lin_w[d][128+j]
__global__ void k_pre(const float* __restrict__ weights, const float* __restrict__ lin_w,
                      float* __restrict__ Wall) {
  int gid = blockIdx.x * 256 + threadIdx.x;   // 384*128 threads
  int k = gid >> 7, d = gid & 127;
  if (k < 128) { Wall[gid] = lin_w[d * 256 + k]; return; }
  const float* wrow = weights + (k - 128) * 128;
  const float* lcol = lin_w + d * 256 + 128;
  float s = 0.f;
  for (int j = 0; j < 128; j++) s += wrow[j] * lcol[j];
  Wall[gid] = s;
}

// ---------------- fused final GEMM: out = lrelu([e|hi|x]@Wall + b) + x0 -------
// 64-node x 128-d tile per block, K phased by 64; thread: 4 nodes x 8 d.
__global__ __launch_bounds__(256, 2)
void k_gemm(const float* __restrict__ ein, const float* __restrict__ hi,
            const float* __restrict__ x, const float* __restrict__ Wall,
            const float* __restrict__ lin_b, const float* __restrict__ x0,
            float* __restrict__ out) {
  __shared__ __align__(16) float Ws[64 * 128];
  __shared__ __align__(16) float Fs[64 * 68];   // stride 68 pads bank conflicts
  int tid = threadIdx.x;
  int n0 = blockIdx.x * 64;
  int d8 = tid & 15;     // d block: d = d8*8 .. d8*8+7
  int n4 = tid >> 4;     // node block: n = n4*4 .. n4*4+3
  float acc[4][8];
  #pragma unroll
  for (int j = 0; j < 4; j++)
    #pragma unroll
    for (int c = 0; c < 8; c++) acc[j][c] = 0.f;

  const float* srcs[3] = {ein, hi, x};
  for (int p = 0; p < 6; p++) {
    // stage 64x128 weight phase
    const float4* W4 = (const float4*)(Wall + p * 64 * 128);
    float4* Ws4 = (float4*)Ws;
    #pragma unroll
    for (int i = 0; i < 8; i++) { int fi = i * 256 + tid; Ws4[fi] = W4[fi]; }
    // stage 64-node x 64-k feature phase
    const float4* src4 = (const float4*)srcs[p >> 1];
    int c0 = (p & 1) * 16;   // float4 column offset into the 128-wide row
    float4* Fs4 = (float4*)Fs;
    #pragma unroll
    for (int i = 0; i < 4; i++) {
      int fi = i * 256 + tid;
      int n = fi >> 4, c4 = fi & 15;
      int gn = n0 + n;
      float4 v = make_float4(0.f, 0.f, 0.f, 0.f);
      if (gn < N_NODES) v = src4[gn * 32 + c0 + c4];
      Fs4[n * 17 + c4] = v;
    }
    __syncthreads();

    for (int kk = 0; kk < 64; kk += 4) {
      float wq[4][8];
      #pragma unroll
      for (int q = 0; q < 4; q++) {
        const float4* wr = (const float4*)(Ws + (kk + q) * 128 + d8 * 8);
        float4 a = wr[0], b = wr[1];
        wq[q][0] = a.x; wq[q][1] = a.y; wq[q][2] = a.z; wq[q][3] = a.w;
        wq[q][4] = b.x; wq[q][5] = b.y; wq[q][6] = b.z; wq[q][7] = b.w;
      }
      #pragma unroll
      for (int j = 0; j < 4; j++) {
        int n = n4 * 4 + j;
        float4 f = *(const float4*)(Fs + n * 68 + kk);
        #pragma unroll
        for (int c = 0; c < 8; c++)
          acc[j][c] += f.x * wq[0][c] + f.y * wq[1][c] + f.z * wq[2][c] + f.w * wq[3][c];
      }
    }
    __syncthreads();
  }

  // epilogue: +bias, leaky relu, +x0
  float bl[8];
  {
    const float4* lb4 = (const float4*)lin_b;
    float4 bA = lb4[d8 * 2], bB = lb4[d8 * 2 + 1];
    bl[0] = bA.x; bl[1] = bA.y; bl[2] = bA.z; bl[3] = bA.w;
    bl[4] = bB.x; bl[5] = bB.y; bl[6] = bB.z; bl[7] = bB.w;
  }
  const float4* x04 = (const float4*)x0;
  float4* out4 = (float4*)out;
  #pragma unroll
  for (int j = 0; j < 4; j++) {
    int gn = n0 + n4 * 4 + j;
    if (gn >= N_NODES) continue;
    float r[8];
    #pragma unroll
    for (int c = 0; c < 8; c++) {
      float v = acc[j][c] + bl[c];
      r[c] = (v > 0.f) ? v : 0.01f * v;
    }
    float4 xa = x04[gn * 32 + d8 * 2], xb = x04[gn * 32 + d8 * 2 + 1];
    out4[gn * 32 + d8 * 2]     = make_float4(r[0] + xa.x, r[1] + xa.y, r[2] + xa.z, r[3] + xa.w);
    out4[gn * 32 + d8 * 2 + 1] = make_float4(r[4] + xb.x, r[5] + xb.y, r[6] + xb.z, r[7] + xb.w);
  }
}

extern "C" void kernel_launch(void* const* d_in, const int* in_sizes, int n_in,
                              void* d_out, int out_size, void* d_ws, size_t ws_size,
                              hipStream_t stream) {
  const int*   src     = (const int*)d_in[0];
  const int*   dst     = (const int*)d_in[1];
  const float* x0      = (const float*)d_in[2];
  const float* x       = (const float*)d_in[3];
  const float* ein     = (const float*)d_in[4];
  // d_in[5] labels, d_in[6] nid: unused by reference output
  const float* alpha   = (const float*)d_in[7];
  const float* emb     = (const float*)d_in[8];
  const float* w1      = (const float*)d_in[9];
  const float* b1      = (const float*)d_in[10];
  const float* w2      = (const float*)d_in[11];
  const float* b2      = (const float*)d_in[12];
  const float* weights = (const float*)d_in[13];
  const float* lin_w   = (const float*)d_in[14];
  const float* lin_b   = (const float*)d_in[15];
  float* out = (float*)d_out;

  // workspace layout (~107 MB)
  float* wf = (float*)d_ws;
  size_t off = 0;
  float* xk   = wf + off; off += (size_t)N_NODES * D;
  float* xk1  = wf + off; off += (size_t)N_NODES * D;
  float* Wall = wf + off; off += (size_t)384 * D;
  float* dinv = wf + off; off += N_NODES;
  int* ib     = (int*)(wf + off);
  int* degs   = ib;                     // N
  int* offs   = ib + N_NODES;           // N
  int* cursor = ib + 2 * N_NODES;       // N
  int* aux    = ib + 3 * N_NODES;       // 512
  int* aux2   = aux + 512;              // 512
  int* csr    = aux2 + 512;             // E

  hipMemsetAsync(degs, 0, sizeof(int) * 3 * (size_t)N_NODES, stream);

  int gE = (N_EDGES + 255) / 256;
  int gN = (N_NODES + 255) / 256;   // 391
  k_deg  <<<gE, 256, 0, stream>>>(dst, degs);
  k_scan1<<<gN, 256, 0, stream>>>(degs, offs, aux);
  k_scan2<<<1, 512, 0, stream>>>(aux, aux2, gN);
  k_scan3<<<gN, 256, 0, stream>>>(offs, aux2, degs, dinv);
  k_fill <<<gE, 256, 0, stream>>>(src, dst, offs, cursor, csr);

  k_mlp<<<1024, 256, 0, stream>>>(x, w1, w2, b1, b2, emb, alpha, xk);
  k_pre<<<192, 256, 0, stream>>>(weights, lin_w, Wall);

  float* hi = out;   // hi lives in d_out (fully written before read; per-row ownership)
  k_gather<1><<<(N_NODES + 3) / 4, 256, 0, stream>>>(xk,  xk1,     hi, csr, offs, degs, dinv);
  k_gather<2><<<(N_NODES + 3) / 4, 256, 0, stream>>>(xk1, nullptr, hi, csr, offs, degs, dinv);

  k_gemm<<<(N_NODES + 63) / 64, 256, 0, stream>>>(ein, hi, x, Wall, lin_b, x0, out);
}

// Round 3
// 665.101 us; speedup vs baseline: 1.1930x; 1.1930x over previous
//
#include <hip/hip_runtime.h>

#define N_NODES 100000
#define N_EDGES 800000
#define D 128

// ---------------- degree count (int atomics) ----------------
__global__ void k_deg(const int* __restrict__ dst, int* __restrict__ degs) {
  int e = blockIdx.x * 256 + threadIdx.x;
  if (e < N_EDGES) atomicAdd(&degs[dst[e]], 1);
}

// ---------------- 2-level exclusive scan over degrees ----------------
__global__ void k_scan1(const int* __restrict__ degs, int* __restrict__ offs,
                        int* __restrict__ aux) {
  __shared__ int s[256];
  int tid = threadIdx.x;
  int i = blockIdx.x * 256 + tid;
  int v = (i < N_NODES) ? degs[i] : 0;
  int sum = v;
  s[tid] = sum; __syncthreads();
  for (int off = 1; off < 256; off <<= 1) {
    int t = (tid >= off) ? s[tid - off] : 0;
    __syncthreads();
    sum += t; s[tid] = sum;
    __syncthreads();
  }
  if (i < N_NODES) offs[i] = sum - v;      // exclusive within block
  if (tid == 255) aux[blockIdx.x] = sum;   // block total
}

__global__ void k_scan2(const int* __restrict__ aux, int* __restrict__ aux2, int nblk) {
  __shared__ int s[512];
  int tid = threadIdx.x;
  int v = (tid < nblk) ? aux[tid] : 0;
  int sum = v;
  s[tid] = sum; __syncthreads();
  for (int off = 1; off < 512; off <<= 1) {
    int t = (tid >= off) ? s[tid - off] : 0;
    __syncthreads();
    sum += t; s[tid] = sum;
    __syncthreads();
  }
  aux2[tid] = sum - v;                     // exclusive block offsets
}

__global__ void k_scan3(int* __restrict__ offs, const int* __restrict__ aux2,
                        const int* __restrict__ degs, float* __restrict__ dinv) {
  int i = blockIdx.x * 256 + threadIdx.x;
  if (i < N_NODES) {
    offs[i] += aux2[blockIdx.x];
    dinv[i] = rsqrtf(fmaxf((float)degs[i], 1.0f));
  }
}

// ---------------- CSR fill (counting sort by dst) ----------------
__global__ void k_fill(const int* __restrict__ src, const int* __restrict__ dst,
                       const int* __restrict__ offs, int* __restrict__ cursor,
                       int* __restrict__ csr) {
  int e = blockIdx.x * 256 + threadIdx.x;
  if (e < N_EDGES) {
    int d = dst[e];
    int pos = offs[d] + atomicAdd(&cursor[d], 1);
    csr[pos] = src[e];
  }
}

// ---------------- per-node MLP -> prob -> xk = x + alpha*x_node ----------------
// Register-tiled GEMM: 64-node tile per block; x staged transposed [k][n] once;
// W1 staged transposed [k][j] in 4 K-phases of 32. Thread: 4 nodes x 8 j.
__global__ __launch_bounds__(256, 2)
void k_mlp(const float* __restrict__ x, const float* __restrict__ w1,
           const float* __restrict__ w2, const float* __restrict__ b1,
           const float* __restrict__ b2, const float* __restrict__ emb,
           const float* __restrict__ alpha_p, float* __restrict__ xk) {
  __shared__ __align__(16) float xsT[128 * 68];    // [k][n], stride 68 (f4-aligned)
  __shared__ __align__(16) float w1sT[32 * 128];   // [k][j] per phase
  __shared__ float zbuf[64];
  __shared__ float pbuf[64];

  int tid = threadIdx.x;
  int lane = tid & 63;
  int wave = tid >> 6;
  int n0 = blockIdx.x * 64;

  // ---- stage x tile transposed: wave w covers k in [w*32, w*32+32) ----
  {
    int n = lane;
    int gn = n0 + n;
    const float4* xr = (const float4*)(x + (size_t)gn * 128 + wave * 32);
    #pragma unroll
    for (int i = 0; i < 8; i++) {
      float4 v = make_float4(0.f, 0.f, 0.f, 0.f);
      if (gn < N_NODES) v = xr[i];
      int k = wave * 32 + i * 4;
      xsT[(k + 0) * 68 + n] = v.x;   // lanes vary in n -> conflict-free
      xsT[(k + 1) * 68 + n] = v.y;
      xsT[(k + 2) * 68 + n] = v.z;
      xsT[(k + 3) * 68 + n] = v.w;
    }
  }

  int d8 = tid & 15;     // j block: j = d8*8 .. +7
  int n4 = tid >> 4;     // node block: n = n4*4 .. +3
  float acc[4][8];
  #pragma unroll
  for (int a = 0; a < 4; a++)
    #pragma unroll
    for (int c = 0; c < 8; c++) acc[a][c] = 0.f;

  for (int p = 0; p < 4; p++) {
    __syncthreads();   // xsT staged / previous phase readers done
    {  // stage W1 phase tile transposed: thread: j = tid>>1, 4 float4 along k
      int j = tid >> 1;
      int kg0 = (tid & 1) * 4;
      const float4* wr = (const float4*)(w1 + j * 128 + p * 32);
      #pragma unroll
      for (int c = 0; c < 4; c++) {
        float4 v = wr[kg0 + c];
        int k = (kg0 + c) * 4;
        w1sT[(k + 0) * 128 + j] = v.x;  // lanes vary in j -> 2-way max (free)
        w1sT[(k + 1) * 128 + j] = v.y;
        w1sT[(k + 2) * 128 + j] = v.z;
        w1sT[(k + 3) * 128 + j] = v.w;
      }
    }
    __syncthreads();

    for (int kk = 0; kk < 32; kk += 4) {
      float wq[4][8];
      float4 f[4];
      #pragma unroll
      for (int q = 0; q < 4; q++) {
        const float4* wr = (const float4*)(w1sT + (kk + q) * 128 + d8 * 8);
        float4 a = wr[0], b = wr[1];
        wq[q][0] = a.x; wq[q][1] = a.y; wq[q][2] = a.z; wq[q][3] = a.w;
        wq[q][4] = b.x; wq[q][5] = b.y; wq[q][6] = b.z; wq[q][7] = b.w;
        // xsT holds GLOBAL k (0..127): index with p*32 + kk + q   (R2 fix)
        f[q] = *(const float4*)(xsT + (p * 32 + kk + q) * 68 + n4 * 4);
      }
      #pragma unroll
      for (int q = 0; q < 4; q++) {
        #pragma unroll
        for (int c = 0; c < 8; c++) {
          acc[0][c] += f[q].x * wq[q][c];
          acc[1][c] += f[q].y * wq[q][c];
          acc[2][c] += f[q].z * wq[q][c];
          acc[3][c] += f[q].w * wq[q][c];
        }
      }
    }
  }

  // ---- bias + relu + wdiff, reduce over j (16 d8-lanes) ----
  {
    int j0 = d8 * 8;
    float bb[8], wd[8];
    #pragma unroll
    for (int c = 0; c < 8; c++) {
      bb[c] = b1[j0 + c];
      wd[c] = w2[128 + j0 + c] - w2[j0 + c];
    }
    #pragma unroll
    for (int a = 0; a < 4; a++) {
      float s = 0.f;
      #pragma unroll
      for (int c = 0; c < 8; c++) {
        float h = fmaxf(acc[a][c] + bb[c], 0.f);
        s += h * wd[c];
      }
      s += __shfl_down(s, 8);
      s += __shfl_down(s, 4);
      s += __shfl_down(s, 2);
      s += __shfl_down(s, 1);
      if (d8 == 0) zbuf[n4 * 4 + a] = s;
    }
  }
  __syncthreads();
  if (tid < 64) {
    float db2 = b2[1] - b2[0];
    float z = zbuf[tid] + db2;
    pbuf[tid] = 1.f / (1.f + expf(-z));
  }
  __syncthreads();

  // ---- epilogue: xk = x + al*((1-p)*e0 + p*e1), coalesced float4 ----
  {
    float al = alpha_p[0];
    int d4 = tid & 31;
    const float4 e0 = ((const float4*)emb)[d4];
    const float4 e1 = ((const float4*)(emb + 128))[d4];
    #pragma unroll
    for (int i = 0; i < 8; i++) {
      int n = i * 8 + (tid >> 5);
      int gn = n0 + n;
      if (gn >= N_NODES) continue;
      float p = pbuf[n];
      float c0 = al * (1.f - p), c1 = al * p;
      float4 xv = ((const float4*)x)[(size_t)gn * 32 + d4];
      float4 o;
      o.x = xv.x + c0 * e0.x + c1 * e1.x;
      o.y = xv.y + c0 * e0.y + c1 * e1.y;
      o.z = xv.z + c0 * e0.z + c1 * e1.z;
      o.w = xv.w + c0 * e0.w + c1 * e1.w;
      ((float4*)xk)[(size_t)gn * 32 + d4] = o;
    }
  }
}

// ---------------- Laplacian gather passes (wave per node, no float atomics) ----
// PASS 1: feat=xk  -> xk1 = xk - dinv*sum ; hi = 0.5*xk + 0.3*xk1
// PASS 2: feat=xk1 -> xk2 = xk1 - dinv*sum; hi += 0.2*xk2
template <int PASS>
__global__ void k_gather(const float* __restrict__ feat, float* __restrict__ feat_out,
                         float* __restrict__ hi, const int* __restrict__ csr,
                         const int* __restrict__ offs, const int* __restrict__ degs,
                         const float* __restrict__ dinv) {
  int node = blockIdx.x * 4 + (threadIdx.x >> 6);
  if (node >= N_NODES) return;
  int lane = threadIdx.x & 63;
  int start = offs[node];
  int cnt = degs[node];
  const float2* f2 = (const float2*)feat;
  float2 acc = make_float2(0.f, 0.f);
  int j = 0;
  for (; j + 1 < cnt; j += 2) {
    int s0 = csr[start + j], s1 = csr[start + j + 1];
    float dv0 = dinv[s0], dv1 = dinv[s1];
    float2 v0 = f2[s0 * 64 + lane];
    float2 v1 = f2[s1 * 64 + lane];
    acc.x += v0.x * dv0 + v1.x * dv1;
    acc.y += v0.y * dv0 + v1.y * dv1;
  }
  if (j < cnt) {
    int s0 = csr[start + j];
    float dv0 = dinv[s0];
    float2 v0 = f2[s0 * 64 + lane];
    acc.x += v0.x * dv0; acc.y += v0.y * dv0;
  }
  float dvi = dinv[node];
  float2 old = f2[node * 64 + lane];
  float2 nw = make_float2(old.x - acc.x * dvi, old.y - acc.y * dvi);
  float2* hi2 = (float2*)hi;
  if (PASS == 1) {
    ((float2*)feat_out)[node * 64 + lane] = nw;
    hi2[node * 64 + lane] = make_float2(0.5f * old.x + 0.3f * nw.x,
                                        0.5f * old.y + 0.3f * nw.y);
  } else {
    float2 h = hi2[node * 64 + lane];
    hi2[node * 64 + lane] = make_float2(h.x + 0.2f * nw.x, h.y + 0.2f * nw.y);
  }
}

// ---------------- precompute merged weight matrix Wall[384][128] -------------
// k<128 : C[k][d] = lin_w[d][k]
// 128<=k<384: Wall[k][d] = sum_j weights[k-128][j] * lin_w[d][128+j]
__global__ void k_pre(const float* __restrict__ weights, const float* __restrict__ lin_w,
                      float* __restrict__ Wall) {
  int gid = blockIdx.x * 256 + threadIdx.x;   // 384*128 threads
  int k = gid >> 7, d = gid & 127;
  if (k < 128) { Wall[gid] = lin_w[d * 256 + k]; return; }
  const float* wrow = weights + (k - 128) * 128;
  const float* lcol = lin_w + d * 256 + 128;
  float s = 0.f;
  for (int j = 0; j < 128; j++) s += wrow[j] * lcol[j];
  Wall[gid] = s;
}

// ---------------- fused final GEMM: out = lrelu([e|hi|x]@Wall + b) + x0 -------
// 64-node x 128-d tile per block, K phased by 64; thread: 4 nodes x 8 d.
__global__ __launch_bounds__(256, 2)
void k_gemm(const float* __restrict__ ein, const float* __restrict__ hi,
            const float* __restrict__ x, const float* __restrict__ Wall,
            const float* __restrict__ lin_b, const float* __restrict__ x0,
            float* __restrict__ out) {
  __shared__ __align__(16) float Ws[64 * 128];
  __shared__ __align__(16) float Fs[64 * 68];   // stride 68 pads bank conflicts
  int tid = threadIdx.x;
  int n0 = blockIdx.x * 64;
  int d8 = tid & 15;     // d block: d = d8*8 .. d8*8+7
  int n4 = tid >> 4;     // node block: n = n4*4 .. n4*4+3
  float acc[4][8];
  #pragma unroll
  for (int j = 0; j < 4; j++)
    #pragma unroll
    for (int c = 0; c < 8; c++) acc[j][c] = 0.f;

  const float* srcs[3] = {ein, hi, x};
  for (int p = 0; p < 6; p++) {
    // stage 64x128 weight phase
    const float4* W4 = (const float4*)(Wall + p * 64 * 128);
    float4* Ws4 = (float4*)Ws;
    #pragma unroll
    for (int i = 0; i < 8; i++) { int fi = i * 256 + tid; Ws4[fi] = W4[fi]; }
    // stage 64-node x 64-k feature phase
    const float4* src4 = (const float4*)srcs[p >> 1];
    int c0 = (p & 1) * 16;   // float4 column offset into the 128-wide row
    float4* Fs4 = (float4*)Fs;
    #pragma unroll
    for (int i = 0; i < 4; i++) {
      int fi = i * 256 + tid;
      int n = fi >> 4, c4 = fi & 15;
      int gn = n0 + n;
      float4 v = make_float4(0.f, 0.f, 0.f, 0.f);
      if (gn < N_NODES) v = src4[gn * 32 + c0 + c4];
      Fs4[n * 17 + c4] = v;
    }
    __syncthreads();

    for (int kk = 0; kk < 64; kk += 4) {
      float wq[4][8];
      #pragma unroll
      for (int q = 0; q < 4; q++) {
        const float4* wr = (const float4*)(Ws + (kk + q) * 128 + d8 * 8);
        float4 a = wr[0], b = wr[1];
        wq[q][0] = a.x; wq[q][1] = a.y; wq[q][2] = a.z; wq[q][3] = a.w;
        wq[q][4] = b.x; wq[q][5] = b.y; wq[q][6] = b.z; wq[q][7] = b.w;
      }
      #pragma unroll
      for (int j = 0; j < 4; j++) {
        int n = n4 * 4 + j;
        float4 f = *(const float4*)(Fs + n * 68 + kk);
        #pragma unroll
        for (int c = 0; c < 8; c++)
          acc[j][c] += f.x * wq[0][c] + f.y * wq[1][c] + f.z * wq[2][c] + f.w * wq[3][c];
      }
    }
    __syncthreads();
  }

  // epilogue: +bias, leaky relu, +x0
  float bl[8];
  {
    const float4* lb4 = (const float4*)lin_b;
    float4 bA = lb4[d8 * 2], bB = lb4[d8 * 2 + 1];
    bl[0] = bA.x; bl[1] = bA.y; bl[2] = bA.z; bl[3] = bA.w;
    bl[4] = bB.x; bl[5] = bB.y; bl[6] = bB.z; bl[7] = bB.w;
  }
  const float4* x04 = (const float4*)x0;
  float4* out4 = (float4*)out;
  #pragma unroll
  for (int j = 0; j < 4; j++) {
    int gn = n0 + n4 * 4 + j;
    if (gn >= N_NODES) continue;
    float r[8];
    #pragma unroll
    for (int c = 0; c < 8; c++) {
      float v = acc[j][c] + bl[c];
      r[c] = (v > 0.f) ? v : 0.01f * v;
    }
    float4 xa = x04[gn * 32 + d8 * 2], xb = x04[gn * 32 + d8 * 2 + 1];
    out4[gn * 32 + d8 * 2]     = make_float4(r[0] + xa.x, r[1] + xa.y, r[2] + xa.z, r[3] + xa.w);
    out4[gn * 32 + d8 * 2 + 1] = make_float4(r[4] + xb.x, r[5] + xb.y, r[6] + xb.z, r[7] + xb.w);
  }
}

extern "C" void kernel_launch(void* const* d_in, const int* in_sizes, int n_in,
                              void* d_out, int out_size, void* d_ws, size_t ws_size,
                              hipStream_t stream) {
  const int*   src     = (const int*)d_in[0];
  const int*   dst     = (const int*)d_in[1];
  const float* x0      = (const float*)d_in[2];
  const float* x       = (const float*)d_in[3];
  const float* ein     = (const float*)d_in[4];
  // d_in[5] labels, d_in[6] nid: unused by reference output
  const float* alpha   = (const float*)d_in[7];
  const float* emb     = (const float*)d_in[8];
  const float* w1      = (const float*)d_in[9];
  const float* b1      = (const float*)d_in[10];
  const float* w2      = (const float*)d_in[11];
  const float* b2      = (const float*)d_in[12];
  const float* weights = (const float*)d_in[13];
  const float* lin_w   = (const float*)d_in[14];
  const float* lin_b   = (const float*)d_in[15];
  float* out = (float*)d_out;

  // workspace layout (~107 MB)
  float* wf = (float*)d_ws;
  size_t off = 0;
  float* xk   = wf + off; off += (size_t)N_NODES * D;
  float* xk1  = wf + off; off += (size_t)N_NODES * D;
  float* Wall = wf + off; off += (size_t)384 * D;
  float* dinv = wf + off; off += N_NODES;
  int* ib     = (int*)(wf + off);
  int* degs   = ib;                     // N
  int* offs   = ib + N_NODES;           // N
  int* cursor = ib + 2 * N_NODES;       // N
  int* aux    = ib + 3 * N_NODES;       // 512
  int* aux2   = aux + 512;              // 512
  int* csr    = aux2 + 512;             // E

  hipMemsetAsync(degs, 0, sizeof(int) * 3 * (size_t)N_NODES, stream);

  int gE = (N_EDGES + 255) / 256;
  int gN = (N_NODES + 255) / 256;   // 391
  k_deg  <<<gE, 256, 0, stream>>>(dst, degs);
  k_scan1<<<gN, 256, 0, stream>>>(degs, offs, aux);
  k_scan2<<<1, 512, 0, stream>>>(aux, aux2, gN);
  k_scan3<<<gN, 256, 0, stream>>>(offs, aux2, degs, dinv);
  k_fill <<<gE, 256, 0, stream>>>(src, dst, offs, cursor, csr);

  k_mlp<<<(N_NODES + 63) / 64, 256, 0, stream>>>(x, w1, w2, b1, b2, emb, alpha, xk);
  k_pre<<<192, 256, 0, stream>>>(weights, lin_w, Wall);

  float* hi = out;   // hi lives in d_out (fully written before read; per-row ownership)
  k_gather<1><<<(N_NODES + 3) / 4, 256, 0, stream>>>(xk,  xk1,     hi, csr, offs, degs, dinv);
  k_gather<2><<<(N_NODES + 3) / 4, 256, 0, stream>>>(xk1, nullptr, hi, csr, offs, degs, dinv);

  k_gemm<<<(N_NODES + 63) / 64, 256, 0, stream>>>(ein, hi, x, Wall, lin_b, x0, out);
}

// Round 4
// 492.825 us; speedup vs baseline: 1.6101x; 1.3496x over previous
//
#include <hip/hip_runtime.h>

#define N_NODES 100000
#define N_EDGES 800000
#define D 128

typedef __attribute__((ext_vector_type(8))) short short8;
typedef __attribute__((ext_vector_type(4))) float f32x4;

__device__ inline unsigned short f2bf(float f) {
  unsigned u = __float_as_uint(f);
  unsigned r = (u + 0x7fffu + ((u >> 16) & 1u)) >> 16;
  return (unsigned short)r;
}
__device__ inline void bfma8(float* acc, const uint4 v, float d) {
  acc[0] = fmaf(__uint_as_float(v.x << 16), d, acc[0]);
  acc[1] = fmaf(__uint_as_float(v.x & 0xffff0000u), d, acc[1]);
  acc[2] = fmaf(__uint_as_float(v.y << 16), d, acc[2]);
  acc[3] = fmaf(__uint_as_float(v.y & 0xffff0000u), d, acc[3]);
  acc[4] = fmaf(__uint_as_float(v.z << 16), d, acc[4]);
  acc[5] = fmaf(__uint_as_float(v.z & 0xffff0000u), d, acc[5]);
  acc[6] = fmaf(__uint_as_float(v.w << 16), d, acc[6]);
  acc[7] = fmaf(__uint_as_float(v.w & 0xffff0000u), d, acc[7]);
}
__device__ inline void unpack8(float* o, const uint4 v) {
  o[0] = __uint_as_float(v.x << 16); o[1] = __uint_as_float(v.x & 0xffff0000u);
  o[2] = __uint_as_float(v.y << 16); o[3] = __uint_as_float(v.y & 0xffff0000u);
  o[4] = __uint_as_float(v.z << 16); o[5] = __uint_as_float(v.z & 0xffff0000u);
  o[6] = __uint_as_float(v.w << 16); o[7] = __uint_as_float(v.w & 0xffff0000u);
}
__device__ inline uint4 pack8(const float* v) {
  uint4 r;
  r.x = (unsigned)f2bf(v[0]) | ((unsigned)f2bf(v[1]) << 16);
  r.y = (unsigned)f2bf(v[2]) | ((unsigned)f2bf(v[3]) << 16);
  r.z = (unsigned)f2bf(v[4]) | ((unsigned)f2bf(v[5]) << 16);
  r.w = (unsigned)f2bf(v[6]) | ((unsigned)f2bf(v[7]) << 16);
  return r;
}

// ---------------- degree count (int atomics) ----------------
__global__ void k_deg(const int* __restrict__ dst, int* __restrict__ degs) {
  int e = blockIdx.x * 256 + threadIdx.x;
  if (e < N_EDGES) atomicAdd(&degs[dst[e]], 1);
}

// ---------------- 2-level exclusive scan over degrees ----------------
__global__ void k_scan1(const int* __restrict__ degs, int* __restrict__ offs,
                        int* __restrict__ aux) {
  __shared__ int s[256];
  int tid = threadIdx.x;
  int i = blockIdx.x * 256 + tid;
  int v = (i < N_NODES) ? degs[i] : 0;
  int sum = v;
  s[tid] = sum; __syncthreads();
  for (int off = 1; off < 256; off <<= 1) {
    int t = (tid >= off) ? s[tid - off] : 0;
    __syncthreads();
    sum += t; s[tid] = sum;
    __syncthreads();
  }
  if (i < N_NODES) offs[i] = sum - v;
  if (tid == 255) aux[blockIdx.x] = sum;
}

__global__ void k_scan2(const int* __restrict__ aux, int* __restrict__ aux2, int nblk) {
  __shared__ int s[512];
  int tid = threadIdx.x;
  int v = (tid < nblk) ? aux[tid] : 0;
  int sum = v;
  s[tid] = sum; __syncthreads();
  for (int off = 1; off < 512; off <<= 1) {
    int t = (tid >= off) ? s[tid - off] : 0;
    __syncthreads();
    sum += t; s[tid] = sum;
    __syncthreads();
  }
  aux2[tid] = sum - v;
}

__global__ void k_scan3(int* __restrict__ offs, const int* __restrict__ aux2,
                        const int* __restrict__ degs, float* __restrict__ dinv) {
  int i = blockIdx.x * 256 + threadIdx.x;
  if (i < N_NODES) {
    offs[i] += aux2[blockIdx.x];
    dinv[i] = rsqrtf(fmaxf((float)degs[i], 1.0f));
  }
}

// ---------------- CSR fill (counting sort by dst) ----------------
__global__ void k_fill(const int* __restrict__ src, const int* __restrict__ dst,
                       const int* __restrict__ offs, int* __restrict__ cursor,
                       int* __restrict__ csr) {
  int e = blockIdx.x * 256 + threadIdx.x;
  if (e < N_EDGES) {
    int d = dst[e];
    int pos = offs[d] + atomicAdd(&cursor[d], 1);
    csr[pos] = src[e];
  }
}

// ---------------- per-node MLP -> prob -> xk(bf16) ----------------
__global__ __launch_bounds__(256, 2)
void k_mlp(const float* __restrict__ x, const float* __restrict__ w1,
           const float* __restrict__ w2, const float* __restrict__ b1,
           const float* __restrict__ b2, const float* __restrict__ emb,
           const float* __restrict__ alpha_p, unsigned short* __restrict__ xk_bf) {
  __shared__ __align__(16) float xsT[128 * 68];
  __shared__ __align__(16) float w1sT[32 * 128];
  __shared__ float zbuf[64];
  __shared__ float pbuf[64];

  int tid = threadIdx.x;
  int lane = tid & 63;
  int wave = tid >> 6;
  int n0 = blockIdx.x * 64;

  {
    int n = lane;
    int gn = n0 + n;
    const float4* xr = (const float4*)(x + (size_t)gn * 128 + wave * 32);
    #pragma unroll
    for (int i = 0; i < 8; i++) {
      float4 v = make_float4(0.f, 0.f, 0.f, 0.f);
      if (gn < N_NODES) v = xr[i];
      int k = wave * 32 + i * 4;
      xsT[(k + 0) * 68 + n] = v.x;
      xsT[(k + 1) * 68 + n] = v.y;
      xsT[(k + 2) * 68 + n] = v.z;
      xsT[(k + 3) * 68 + n] = v.w;
    }
  }

  int d8 = tid & 15;
  int n4 = tid >> 4;
  float acc[4][8];
  #pragma unroll
  for (int a = 0; a < 4; a++)
    #pragma unroll
    for (int c = 0; c < 8; c++) acc[a][c] = 0.f;

  for (int p = 0; p < 4; p++) {
    __syncthreads();
    {
      int j = tid >> 1;
      int kg0 = (tid & 1) * 4;
      const float4* wr = (const float4*)(w1 + j * 128 + p * 32);
      #pragma unroll
      for (int c = 0; c < 4; c++) {
        float4 v = wr[kg0 + c];
        int k = (kg0 + c) * 4;
        w1sT[(k + 0) * 128 + j] = v.x;
        w1sT[(k + 1) * 128 + j] = v.y;
        w1sT[(k + 2) * 128 + j] = v.z;
        w1sT[(k + 3) * 128 + j] = v.w;
      }
    }
    __syncthreads();

    for (int kk = 0; kk < 32; kk += 4) {
      float wq[4][8];
      float4 f[4];
      #pragma unroll
      for (int q = 0; q < 4; q++) {
        const float4* wr = (const float4*)(w1sT + (kk + q) * 128 + d8 * 8);
        float4 a = wr[0], b = wr[1];
        wq[q][0] = a.x; wq[q][1] = a.y; wq[q][2] = a.z; wq[q][3] = a.w;
        wq[q][4] = b.x; wq[q][5] = b.y; wq[q][6] = b.z; wq[q][7] = b.w;
        f[q] = *(const float4*)(xsT + (p * 32 + kk + q) * 68 + n4 * 4);
      }
      #pragma unroll
      for (int q = 0; q < 4; q++) {
        #pragma unroll
        for (int c = 0; c < 8; c++) {
          acc[0][c] += f[q].x * wq[q][c];
          acc[1][c] += f[q].y * wq[q][c];
          acc[2][c] += f[q].z * wq[q][c];
          acc[3][c] += f[q].w * wq[q][c];
        }
      }
    }
  }

  {
    int j0 = d8 * 8;
    float bb[8], wd[8];
    #pragma unroll
    for (int c = 0; c < 8; c++) {
      bb[c] = b1[j0 + c];
      wd[c] = w2[128 + j0 + c] - w2[j0 + c];
    }
    #pragma unroll
    for (int a = 0; a < 4; a++) {
      float s = 0.f;
      #pragma unroll
      for (int c = 0; c < 8; c++) {
        float h = fmaxf(acc[a][c] + bb[c], 0.f);
        s += h * wd[c];
      }
      s += __shfl_down(s, 8);
      s += __shfl_down(s, 4);
      s += __shfl_down(s, 2);
      s += __shfl_down(s, 1);
      if (d8 == 0) zbuf[n4 * 4 + a] = s;
    }
  }
  __syncthreads();
  if (tid < 64) {
    float db2 = b2[1] - b2[0];
    float z = zbuf[tid] + db2;
    pbuf[tid] = 1.f / (1.f + expf(-z));
  }
  __syncthreads();

  {
    float al = alpha_p[0];
    int d4 = tid & 31;
    const float4 e0 = ((const float4*)emb)[d4];
    const float4 e1 = ((const float4*)(emb + 128))[d4];
    #pragma unroll
    for (int i = 0; i < 8; i++) {
      int n = i * 8 + (tid >> 5);
      int gn = n0 + n;
      if (gn >= N_NODES) continue;
      float p = pbuf[n];
      float c0 = al * (1.f - p), c1 = al * p;
      float4 xv = ((const float4*)x)[(size_t)gn * 32 + d4];
      float o0 = xv.x + c0 * e0.x + c1 * e1.x;
      float o1 = xv.y + c0 * e0.y + c1 * e1.y;
      float o2 = xv.z + c0 * e0.z + c1 * e1.z;
      float o3 = xv.w + c0 * e0.w + c1 * e1.w;
      ushort4 ov = make_ushort4(f2bf(o0), f2bf(o1), f2bf(o2), f2bf(o3));
      ((ushort4*)xk_bf)[(size_t)gn * 32 + d4] = ov;
    }
  }
}

// ---------------- Laplacian gather passes, bf16 feat, 4 edges/instr ----------
// PASS 1: feat=xk  -> xk1(bf16) = xk - dinv*sum ; hi(fp32,d_out) = .5 xk + .3 xk1
// PASS 2: feat=xk1 -> xk2 = xk1 - dinv*sum; ahi(bf16) = hi + .2 xk2
template <int PASS>
__global__ __launch_bounds__(256)
void k_gather(const unsigned short* __restrict__ feat,
              unsigned short* __restrict__ feat_out,
              float* __restrict__ hi,
              unsigned short* __restrict__ ahi,
              const int* __restrict__ csr, const int* __restrict__ offs,
              const int* __restrict__ degs, const float* __restrict__ dinv) {
  int node = blockIdx.x * 4 + (threadIdx.x >> 6);
  int lane = threadIdx.x & 63;
  int quad = lane >> 4;
  int l16 = lane & 15;
  int start = offs[node];
  int cnt = degs[node];
  const uint4* f16 = (const uint4*)feat;   // one row = 16 uint4
  float acc[8];
  #pragma unroll
  for (int i = 0; i < 8; i++) acc[i] = 0.f;

  int j = 0;
  for (; j + 8 <= cnt; j += 8) {            // 8 edges in flight
    int sa = csr[start + j + quad];
    int sb = csr[start + j + 4 + quad];
    float da = dinv[sa], db = dinv[sb];
    uint4 va = f16[(size_t)sa * 16 + l16];
    uint4 vb = f16[(size_t)sb * 16 + l16];
    bfma8(acc, va, da);
    bfma8(acc, vb, db);
  }
  if (j + 4 <= cnt) {
    int s = csr[start + j + quad];
    float d = dinv[s];
    uint4 v = f16[(size_t)s * 16 + l16];
    bfma8(acc, v, d);
    j += 4;
  }
  int rem = cnt - j;                        // 0..3
  if (quad < rem) {
    int s = csr[start + j + quad];
    float d = dinv[s];
    uint4 v = f16[(size_t)s * 16 + l16];
    bfma8(acc, v, d);
  }

  #pragma unroll
  for (int i = 0; i < 8; i++) {
    acc[i] += __shfl_down(acc[i], 32);
    acc[i] += __shfl_down(acc[i], 16);
  }

  if (quad == 0) {
    float dvi = dinv[node];
    float old[8], nw[8];
    unpack8(old, f16[(size_t)node * 16 + l16]);
    #pragma unroll
    for (int i = 0; i < 8; i++) nw[i] = old[i] - acc[i] * dvi;
    if (PASS == 1) {
      ((uint4*)feat_out)[(size_t)node * 16 + l16] = pack8(nw);
      float h[8];
      #pragma unroll
      for (int i = 0; i < 8; i++) h[i] = 0.5f * old[i] + 0.3f * nw[i];
      float4* hp = (float4*)(hi + (size_t)node * 128 + l16 * 8);
      hp[0] = make_float4(h[0], h[1], h[2], h[3]);
      hp[1] = make_float4(h[4], h[5], h[6], h[7]);
    } else {
      const float4* hp = (const float4*)(hi + (size_t)node * 128 + l16 * 8);
      float4 a = hp[0], b = hp[1];
      float h[8] = {a.x, a.y, a.z, a.w, b.x, b.y, b.z, b.w};
      #pragma unroll
      for (int i = 0; i < 8; i++) h[i] += 0.2f * nw[i];
      ((uint4*)ahi)[(size_t)node * 16 + l16] = pack8(h);
    }
  }
}

// ---------------- precompute merged weights -> bf16, transposed, stride 392 --
// wbt[d][k] (d in [0,128), k in [0,384), row stride 392):
//   k<128 : lin_w[d][k]
//   else  : sum_j weights[k-128][j] * lin_w[d][128+j]
__global__ void k_pre(const float* __restrict__ weights, const float* __restrict__ lin_w,
                      unsigned short* __restrict__ wbt) {
  int gid = blockIdx.x * 256 + threadIdx.x;   // 384*128 threads
  int k = gid >> 7, d = gid & 127;
  float v;
  if (k < 128) {
    v = lin_w[d * 256 + k];
  } else {
    const float* wrow = weights + (k - 128) * 128;
    const float* lcol = lin_w + d * 256 + 128;
    float s = 0.f;
    for (int j = 0; j < 128; j++) s += wrow[j] * lcol[j];
    v = s;
  }
  wbt[d * 392 + k] = f2bf(v);
}

// ---------------- fused final GEMM via MFMA bf16 ------------------------------
// out = lrelu([ein | ahi | x] @ Wall + lin_b) + x0
// block: 4 waves x (16 rows x 128 cols); K=384 in 12 steps of 32.
// B staged in LDS in two 64-col halves (stride 392 kills bank conflicts).
__global__ __launch_bounds__(256, 2)
void k_gemm2(const float* __restrict__ ein, const unsigned short* __restrict__ ahi,
             const float* __restrict__ x, const unsigned short* __restrict__ wbt,
             const float* __restrict__ lin_b, const float* __restrict__ x0,
             float* __restrict__ out) {
  __shared__ __align__(16) unsigned short Bs[64 * 392];
  int tid = threadIdx.x;
  int lane = tid & 63, wv = tid >> 6;
  int quad = lane >> 4, l16 = lane & 15;
  int n0 = blockIdx.x * 64;
  int rA = n0 + wv * 16 + l16;
  if (rA >= N_NODES) rA = N_NODES - 1;      // clamped dup; store-guarded
  int kq = quad * 8;

  // ---- 12 a_frags in registers (A row = rA) ----
  short8 af[12];
  #pragma unroll
  for (int kb = 0; kb < 4; kb++) {          // cols 0-127: ein (fp32 -> bf16)
    const float4* p = (const float4*)(ein + (size_t)rA * 128 + kb * 32 + kq);
    float4 a = p[0], b = p[1];
    short8 t;
    t[0] = (short)f2bf(a.x); t[1] = (short)f2bf(a.y);
    t[2] = (short)f2bf(a.z); t[3] = (short)f2bf(a.w);
    t[4] = (short)f2bf(b.x); t[5] = (short)f2bf(b.y);
    t[6] = (short)f2bf(b.z); t[7] = (short)f2bf(b.w);
    af[kb] = t;
  }
  #pragma unroll
  for (int kb = 0; kb < 4; kb++)            // cols 128-255: ahi (bf16)
    af[4 + kb] = *(const short8*)(ahi + (size_t)rA * 128 + kb * 32 + kq);
  #pragma unroll
  for (int kb = 0; kb < 4; kb++) {          // cols 256-383: x (fp32 -> bf16)
    const float4* p = (const float4*)(x + (size_t)rA * 128 + kb * 32 + kq);
    float4 a = p[0], b = p[1];
    short8 t;
    t[0] = (short)f2bf(a.x); t[1] = (short)f2bf(a.y);
    t[2] = (short)f2bf(a.z); t[3] = (short)f2bf(a.w);
    t[4] = (short)f2bf(b.x); t[5] = (short)f2bf(b.y);
    t[6] = (short)f2bf(b.z); t[7] = (short)f2bf(b.w);
    af[8 + kb] = t;
  }

  f32x4 acc[8];
  #pragma unroll
  for (int i = 0; i < 8; i++) acc[i] = (f32x4){0.f, 0.f, 0.f, 0.f};

  for (int h = 0; h < 2; h++) {
    if (h) __syncthreads();
    {  // stage B half: rows (cols of Wall) h*64 .. h*64+63, 49 uint4 each
      const uint4* W = (const uint4*)wbt;
      uint4* B4 = (uint4*)Bs;
      int r = tid >> 2, c0 = tid & 3;
      #pragma unroll
      for (int i = 0; i < 13; i++) {
        int c = c0 + i * 4;
        if (c < 49) B4[r * 49 + c] = W[(h * 64 + r) * 49 + c];
      }
    }
    __syncthreads();
    #pragma unroll
    for (int kb = 0; kb < 12; kb++) {
      short8 a = af[kb];
      #pragma unroll
      for (int t = 0; t < 4; t++) {
        short8 b = *(const short8*)(Bs + (t * 16 + l16) * 392 + kb * 32 + kq);
        acc[h * 4 + t] = __builtin_amdgcn_mfma_f32_16x16x32_bf16(a, b, acc[h * 4 + t], 0, 0, 0);
      }
    }
  }

  // ---- epilogue: +bias, lrelu, +x0 ----
  #pragma unroll
  for (int idx = 0; idx < 8; idx++) {
    int col = (idx >> 2) * 64 + (idx & 3) * 16 + l16;
    float bl = lin_b[col];
    #pragma unroll
    for (int r = 0; r < 4; r++) {
      int gn = n0 + wv * 16 + quad * 4 + r;
      if (gn < N_NODES) {
        float v = acc[idx][r] + bl;
        v = (v > 0.f) ? v : 0.01f * v;
        out[(size_t)gn * 128 + col] = v + x0[(size_t)gn * 128 + col];
      }
    }
  }
}

extern "C" void kernel_launch(void* const* d_in, const int* in_sizes, int n_in,
                              void* d_out, int out_size, void* d_ws, size_t ws_size,
                              hipStream_t stream) {
  const int*   src     = (const int*)d_in[0];
  const int*   dst     = (const int*)d_in[1];
  const float* x0      = (const float*)d_in[2];
  const float* x       = (const float*)d_in[3];
  const float* ein     = (const float*)d_in[4];
  const float* alpha   = (const float*)d_in[7];
  const float* emb     = (const float*)d_in[8];
  const float* w1      = (const float*)d_in[9];
  const float* b1      = (const float*)d_in[10];
  const float* w2      = (const float*)d_in[11];
  const float* b2      = (const float*)d_in[12];
  const float* weights = (const float*)d_in[13];
  const float* lin_w   = (const float*)d_in[14];
  const float* lin_b   = (const float*)d_in[15];
  float* out = (float*)d_out;

  // workspace layout (~82 MB)
  unsigned short* xk_bf  = (unsigned short*)d_ws;             // N*128 bf16
  unsigned short* xk1_bf = xk_bf  + (size_t)N_NODES * 128;
  unsigned short* ahi    = xk1_bf + (size_t)N_NODES * 128;
  unsigned short* wbt    = ahi    + (size_t)N_NODES * 128;    // 128*392 bf16
  float* dinv = (float*)(wbt + 128 * 392);
  int* degs   = (int*)(dinv + N_NODES);
  int* offs   = degs + N_NODES;
  int* cursor = offs + N_NODES;
  int* aux    = cursor + N_NODES;
  int* aux2   = aux + 512;
  int* csr    = aux2 + 512;

  hipMemsetAsync(degs, 0, sizeof(int) * 3 * (size_t)N_NODES, stream);

  int gE = (N_EDGES + 255) / 256;
  int gN = (N_NODES + 255) / 256;   // 391
  k_deg  <<<gE, 256, 0, stream>>>(dst, degs);
  k_scan1<<<gN, 256, 0, stream>>>(degs, offs, aux);
  k_scan2<<<1, 512, 0, stream>>>(aux, aux2, gN);
  k_scan3<<<gN, 256, 0, stream>>>(offs, aux2, degs, dinv);
  k_fill <<<gE, 256, 0, stream>>>(src, dst, offs, cursor, csr);

  k_mlp<<<(N_NODES + 63) / 64, 256, 0, stream>>>(x, w1, w2, b1, b2, emb, alpha, xk_bf);
  k_pre<<<192, 256, 0, stream>>>(weights, lin_w, wbt);

  float* hi = out;   // fp32 hi lives in d_out between pass1 and gemm
  k_gather<1><<<N_NODES / 4, 256, 0, stream>>>(xk_bf,  xk1_bf, hi, nullptr, csr, offs, degs, dinv);
  k_gather<2><<<N_NODES / 4, 256, 0, stream>>>(xk1_bf, nullptr, hi, ahi,    csr, offs, degs, dinv);

  k_gemm2<<<(N_NODES + 63) / 64, 256, 0, stream>>>(ein, ahi, x, wbt, lin_b, x0, out);
}